// Round 1
// baseline (1265.838 us; speedup 1.0000x reference)
//
#include <hip/hip_runtime.h>

#define NN 50000
#define DD 128
#define EE 800000

// ---------------- CSR build ----------------
__global__ void hist_kernel(const int* __restrict__ dst, int* __restrict__ cnt, int E) {
    int e = blockIdx.x * blockDim.x + threadIdx.x;
    if (e < E) atomicAdd(&cnt[dst[e]], 1);
}

// Single-block chunked Hillis-Steele scan over cnt[n] -> exclusive rowptr, pos copy, 1/deg.
__global__ void scan_kernel(const int* __restrict__ cnt, int* __restrict__ rowptr,
                            int* __restrict__ pos, float* __restrict__ inv_cnt,
                            int n, int E) {
    __shared__ int sdata[256];
    __shared__ int carry;
    if (threadIdx.x == 0) carry = 0;
    __syncthreads();
    for (int base = 0; base < n; base += 256) {
        int i = base + (int)threadIdx.x;
        int v = (i < n) ? cnt[i] : 0;
        sdata[threadIdx.x] = v;
        __syncthreads();
        for (int off = 1; off < 256; off <<= 1) {
            int t = (threadIdx.x >= (unsigned)off) ? sdata[threadIdx.x - off] : 0;
            __syncthreads();
            sdata[threadIdx.x] += t;
            __syncthreads();
        }
        int excl = sdata[threadIdx.x] - v;
        if (i < n) {
            rowptr[i] = carry + excl;
            pos[i]    = carry + excl;
            inv_cnt[i] = (v > 0) ? (1.0f / (float)v) : 0.0f;
        }
        __syncthreads();
        if (threadIdx.x == 255) carry += sdata[255];
        __syncthreads();
    }
    if (threadIdx.x == 0) rowptr[n] = E;
}

__global__ void bucket_kernel(const int* __restrict__ src, const int* __restrict__ dst,
                              int* __restrict__ pos, int* __restrict__ eidx, int E) {
    int e = blockIdx.x * blockDim.x + threadIdx.x;
    if (e < E) {
        int p = atomicAdd(&pos[dst[e]], 1);
        eidx[p] = src[e];
    }
}

// ---------------- mean aggregation: one wave per node ----------------
__global__ __launch_bounds__(256) void agg_kernel(const float* __restrict__ h,
                                                  const int* __restrict__ eidx,
                                                  const int* __restrict__ rowptr,
                                                  const float* __restrict__ inv_cnt,
                                                  float* __restrict__ agg, int n) {
    int node = blockIdx.x * 4 + (threadIdx.x >> 6);
    if (node >= n) return;
    int lane = threadIdx.x & 63;
    int s0 = rowptr[node], s1 = rowptr[node + 1];
    float ax = 0.f, ay = 0.f;
    for (int e = s0; e < s1; ++e) {
        int s = eidx[e];
        float2 v = *((const float2*)(h + (size_t)s * DD) + lane);
        ax += v.x; ay += v.y;
    }
    float inv = inv_cnt[node];
    float2 o; o.x = ax * inv; o.y = ay * inv;
    *((float2*)(agg + (size_t)node * DD) + lane) = o;
}

// ---------------- fused dual-GEMM: out = agg@Wl^T + h@Wr^T + b (opt ReLU) ----------------
// Block: 256 threads, 32 rows x 128 cols tile; per-thread 4x4 micro-tile.
// Rows staged in LDS before any global write -> in-place (h == out) is safe.
template <int RELU>
__global__ __launch_bounds__(256) void linear_kernel(const float* __restrict__ agg,
                                                     const float* __restrict__ h,
                                                     const float* __restrict__ Wl,
                                                     const float* __restrict__ Wr,
                                                     const float* __restrict__ b,
                                                     float* __restrict__ out, int n) {
    __shared__ float sA[32][DD];
    __shared__ float sH[32][DD];
    const int row0 = blockIdx.x * 32;
    const int tid = threadIdx.x;

    // stage 32x128 agg and h rows (float4 flat copy, zero-fill past n)
    for (int j = 0; j < 4; ++j) {
        int idx = tid + j * 256;          // float4 index, 1024 per tile
        int r = idx >> 5;                 // (idx*4)/128
        float4 va = {0.f, 0.f, 0.f, 0.f}, vh = {0.f, 0.f, 0.f, 0.f};
        if (row0 + r < n) {
            va = ((const float4*)(agg + (size_t)row0 * DD))[idx];
            vh = ((const float4*)(h   + (size_t)row0 * DD))[idx];
        }
        ((float4*)&sA[0][0])[idx] = va;
        ((float4*)&sH[0][0])[idx] = vh;
    }
    __syncthreads();

    const int tc = (tid & 31) * 4;   // col base
    const int tr = (tid >> 5) * 4;   // row base within tile
    float acc[4][4] = {};

    for (int k = 0; k < DD; k += 4) {
        float4 a[4], hh[4], wl[4], wr[4];
#pragma unroll
        for (int r = 0; r < 4; ++r) {
            a[r]  = *(const float4*)&sA[tr + r][k];
            hh[r] = *(const float4*)&sH[tr + r][k];
        }
#pragma unroll
        for (int c = 0; c < 4; ++c) {
            wl[c] = *(const float4*)&Wl[(size_t)(tc + c) * DD + k];
            wr[c] = *(const float4*)&Wr[(size_t)(tc + c) * DD + k];
        }
#pragma unroll
        for (int r = 0; r < 4; ++r)
#pragma unroll
            for (int c = 0; c < 4; ++c) {
                acc[r][c] += a[r].x * wl[c].x + a[r].y * wl[c].y +
                             a[r].z * wl[c].z + a[r].w * wl[c].w +
                             hh[r].x * wr[c].x + hh[r].y * wr[c].y +
                             hh[r].z * wr[c].z + hh[r].w * wr[c].w;
            }
    }

#pragma unroll
    for (int r = 0; r < 4; ++r) {
        int gr = row0 + tr + r;
        if (gr < n) {
#pragma unroll
            for (int c = 0; c < 4; ++c) {
                float v = acc[r][c] + b[tc + c];
                if (RELU) v = fmaxf(v, 0.f);
                out[(size_t)gr * DD + tc + c] = v;
            }
        }
    }
}

extern "C" void kernel_launch(void* const* d_in, const int* in_sizes, int n_in,
                              void* d_out, int out_size, void* d_ws, size_t ws_size,
                              hipStream_t stream) {
    const float* x    = (const float*)d_in[0];
    const int*   edge = (const int*)d_in[1];     // [2, E] int32 (jax x64 disabled)
    const int*   srcp = edge;
    const int*   dstp = edge + EE;
    const float* W1l = (const float*)d_in[2];
    const float* b1  = (const float*)d_in[3];
    const float* W1r = (const float*)d_in[4];
    const float* W2l = (const float*)d_in[5];
    const float* b2  = (const float*)d_in[6];
    const float* W2r = (const float*)d_in[7];
    const float* W3l = (const float*)d_in[8];
    const float* b3  = (const float*)d_in[9];
    const float* W3r = (const float*)d_in[10];
    float* out = (float*)d_out;

    // workspace layout (256B-aligned chunks)
    char* ws = (char*)d_ws;
    size_t off = 0;
    auto alloc = [&](size_t bytes) { void* p = ws + off; off += (bytes + 255) & ~(size_t)255; return p; };
    int*   eidx    = (int*)  alloc((size_t)EE * 4);
    int*   rowptr  = (int*)  alloc((size_t)(NN + 1) * 4);
    int*   pos     = (int*)  alloc((size_t)NN * 4);
    int*   cnt     = (int*)  alloc((size_t)NN * 4);
    float* inv_cnt = (float*)alloc((size_t)NN * 4);
    float* agg     = (float*)alloc((size_t)NN * DD * 4);
    float* h1      = (float*)alloc((size_t)NN * DD * 4);

    hipMemsetAsync(cnt, 0, (size_t)NN * 4, stream);
    hist_kernel<<<(EE + 255) / 256, 256, 0, stream>>>(dstp, cnt, EE);
    scan_kernel<<<1, 256, 0, stream>>>(cnt, rowptr, pos, inv_cnt, NN, EE);
    bucket_kernel<<<(EE + 255) / 256, 256, 0, stream>>>(srcp, dstp, pos, eidx, EE);

    const int agg_grid = (NN + 3) / 4;
    const int lin_grid = (NN + 31) / 32;

    // layer 1: x -> h1 (ReLU)
    agg_kernel<<<agg_grid, 256, 0, stream>>>(x, eidx, rowptr, inv_cnt, agg, NN);
    linear_kernel<1><<<lin_grid, 256, 0, stream>>>(agg, x, W1l, W1r, b1, h1, NN);

    // layer 2: h1 -> d_out (ReLU)
    agg_kernel<<<agg_grid, 256, 0, stream>>>(h1, eidx, rowptr, inv_cnt, agg, NN);
    linear_kernel<1><<<lin_grid, 256, 0, stream>>>(agg, h1, W2l, W2r, b2, out, NN);

    // layer 3: d_out -> d_out (no ReLU; in-place safe via LDS staging)
    agg_kernel<<<agg_grid, 256, 0, stream>>>(out, eidx, rowptr, inv_cnt, agg, NN);
    linear_kernel<0><<<lin_grid, 256, 0, stream>>>(agg, out, W3l, W3r, b3, out, NN);
}

// Round 2
// 954.641 us; speedup vs baseline: 1.3260x; 1.3260x over previous
//
#include <hip/hip_runtime.h>

#define NN 50000
#define DD 128
#define EE 800000
#define SCAN_BLK 256
#define N_SBLOCKS ((NN + SCAN_BLK - 1) / SCAN_BLK)   // 196

// ---------------- CSR build ----------------
__global__ void hist_kernel(const int* __restrict__ dst, int* __restrict__ cnt, int E) {
    int e = blockIdx.x * blockDim.x + threadIdx.x;
    if (e < E) atomicAdd(&cnt[dst[e]], 1);
}

// Phase 1: per-block sums of cnt
__global__ __launch_bounds__(SCAN_BLK) void block_reduce_kernel(const int* __restrict__ cnt,
                                                                int* __restrict__ bsums, int n) {
    __shared__ int s[SCAN_BLK];
    int i = blockIdx.x * SCAN_BLK + threadIdx.x;
    int v = (i < n) ? cnt[i] : 0;
    s[threadIdx.x] = v;
    __syncthreads();
    for (int off = SCAN_BLK / 2; off > 0; off >>= 1) {
        if (threadIdx.x < (unsigned)off) s[threadIdx.x] += s[threadIdx.x + off];
        __syncthreads();
    }
    if (threadIdx.x == 0) bsums[blockIdx.x] = s[0];
}

// Phase 2: exclusive scan of block sums (nb <= 256), single block
__global__ __launch_bounds__(SCAN_BLK) void scan_bsums_kernel(int* __restrict__ bsums, int nb) {
    __shared__ int s[SCAN_BLK];
    int v = (threadIdx.x < (unsigned)nb) ? bsums[threadIdx.x] : 0;
    s[threadIdx.x] = v;
    __syncthreads();
    for (int off = 1; off < SCAN_BLK; off <<= 1) {
        int t = (threadIdx.x >= (unsigned)off) ? s[threadIdx.x - off] : 0;
        __syncthreads();
        s[threadIdx.x] += t;
        __syncthreads();
    }
    if (threadIdx.x < (unsigned)nb) bsums[threadIdx.x] = s[threadIdx.x] - v;  // exclusive
}

// Phase 3: per-block exclusive scan + block offset -> rowptr/pos/inv_cnt
__global__ __launch_bounds__(SCAN_BLK) void block_scan_kernel(const int* __restrict__ cnt,
                                                              const int* __restrict__ bsums,
                                                              int* __restrict__ rowptr,
                                                              int* __restrict__ pos,
                                                              float* __restrict__ inv_cnt,
                                                              int n, int E) {
    __shared__ int s[SCAN_BLK];
    int i = blockIdx.x * SCAN_BLK + threadIdx.x;
    int v = (i < n) ? cnt[i] : 0;
    s[threadIdx.x] = v;
    __syncthreads();
    for (int off = 1; off < SCAN_BLK; off <<= 1) {
        int t = (threadIdx.x >= (unsigned)off) ? s[threadIdx.x - off] : 0;
        __syncthreads();
        s[threadIdx.x] += t;
        __syncthreads();
    }
    int excl = bsums[blockIdx.x] + s[threadIdx.x] - v;
    if (i < n) {
        rowptr[i] = excl;
        pos[i]    = excl;
        inv_cnt[i] = (v > 0) ? (1.0f / (float)v) : 0.0f;
        if (i == n - 1) rowptr[n] = E;
    }
}

__global__ void bucket_kernel(const int* __restrict__ src, const int* __restrict__ dst,
                              int* __restrict__ pos, int* __restrict__ eidx, int E) {
    int e = blockIdx.x * blockDim.x + threadIdx.x;
    if (e < E) {
        int p = atomicAdd(&pos[dst[e]], 1);
        eidx[p] = src[e];
    }
}

// ---------------- mean aggregation ----------------
// One wave per node. Half-wave (32 lanes x float4 = 512B) covers one row;
// halves take even/odd edges; 2x manual unroll -> 4 row-loads in flight.
__global__ __launch_bounds__(256) void agg_kernel(const float* __restrict__ h,
                                                  const int* __restrict__ eidx,
                                                  const int* __restrict__ rowptr,
                                                  const float* __restrict__ inv_cnt,
                                                  float* __restrict__ agg, int n) {
    int node = blockIdx.x * 4 + (threadIdx.x >> 6);
    if (node >= n) return;
    int lane = threadIdx.x & 63;
    int half = lane >> 5;       // which edge parity this half-wave takes
    int q = lane & 31;          // float4 index within the 128-float row
    int s0 = rowptr[node], s1 = rowptr[node + 1];
    float4 acc = {0.f, 0.f, 0.f, 0.f};
    int e = s0 + half;
    while (e + 2 < s1) {
        int sA = eidx[e], sB = eidx[e + 2];
        float4 vA = ((const float4*)(h + (size_t)sA * DD))[q];
        float4 vB = ((const float4*)(h + (size_t)sB * DD))[q];
        acc.x += vA.x + vB.x; acc.y += vA.y + vB.y;
        acc.z += vA.z + vB.z; acc.w += vA.w + vB.w;
        e += 4;
    }
    if (e < s1) {
        int sA = eidx[e];
        float4 vA = ((const float4*)(h + (size_t)sA * DD))[q];
        acc.x += vA.x; acc.y += vA.y; acc.z += vA.z; acc.w += vA.w;
    }
    // combine even/odd halves (lane q and lane q+32 hold same float4 slot)
    acc.x += __shfl_xor(acc.x, 32);
    acc.y += __shfl_xor(acc.y, 32);
    acc.z += __shfl_xor(acc.z, 32);
    acc.w += __shfl_xor(acc.w, 32);
    if (half == 0) {
        float inv = inv_cnt[node];
        float4 o = {acc.x * inv, acc.y * inv, acc.z * inv, acc.w * inv};
        ((float4*)(agg + (size_t)node * DD))[q] = o;
    }
}

// ---------------- fused dual-GEMM: out = agg@Wl^T + h@Wr^T + b (opt ReLU) ----------------
template <int RELU>
__global__ __launch_bounds__(256) void linear_kernel(const float* __restrict__ agg,
                                                     const float* __restrict__ h,
                                                     const float* __restrict__ Wl,
                                                     const float* __restrict__ Wr,
                                                     const float* __restrict__ b,
                                                     float* __restrict__ out, int n) {
    __shared__ float sA[32][DD];
    __shared__ float sH[32][DD];
    const int row0 = blockIdx.x * 32;
    const int tid = threadIdx.x;

    for (int j = 0; j < 4; ++j) {
        int idx = tid + j * 256;
        int r = idx >> 5;
        float4 va = {0.f, 0.f, 0.f, 0.f}, vh = {0.f, 0.f, 0.f, 0.f};
        if (row0 + r < n) {
            va = ((const float4*)(agg + (size_t)row0 * DD))[idx];
            vh = ((const float4*)(h   + (size_t)row0 * DD))[idx];
        }
        ((float4*)&sA[0][0])[idx] = va;
        ((float4*)&sH[0][0])[idx] = vh;
    }
    __syncthreads();

    const int tc = (tid & 31) * 4;
    const int tr = (tid >> 5) * 4;
    float acc[4][4] = {};

    for (int k = 0; k < DD; k += 4) {
        float4 a[4], hh[4], wl[4], wr[4];
#pragma unroll
        for (int r = 0; r < 4; ++r) {
            a[r]  = *(const float4*)&sA[tr + r][k];
            hh[r] = *(const float4*)&sH[tr + r][k];
        }
#pragma unroll
        for (int c = 0; c < 4; ++c) {
            wl[c] = *(const float4*)&Wl[(size_t)(tc + c) * DD + k];
            wr[c] = *(const float4*)&Wr[(size_t)(tc + c) * DD + k];
        }
#pragma unroll
        for (int r = 0; r < 4; ++r)
#pragma unroll
            for (int c = 0; c < 4; ++c) {
                acc[r][c] += a[r].x * wl[c].x + a[r].y * wl[c].y +
                             a[r].z * wl[c].z + a[r].w * wl[c].w +
                             hh[r].x * wr[c].x + hh[r].y * wr[c].y +
                             hh[r].z * wr[c].z + hh[r].w * wr[c].w;
            }
    }

#pragma unroll
    for (int r = 0; r < 4; ++r) {
        int gr = row0 + tr + r;
        if (gr < n) {
#pragma unroll
            for (int c = 0; c < 4; ++c) {
                float v = acc[r][c] + b[tc + c];
                if (RELU) v = fmaxf(v, 0.f);
                out[(size_t)gr * DD + tc + c] = v;
            }
        }
    }
}

extern "C" void kernel_launch(void* const* d_in, const int* in_sizes, int n_in,
                              void* d_out, int out_size, void* d_ws, size_t ws_size,
                              hipStream_t stream) {
    const float* x    = (const float*)d_in[0];
    const int*   edge = (const int*)d_in[1];     // [2, E] int32
    const int*   srcp = edge;
    const int*   dstp = edge + EE;
    const float* W1l = (const float*)d_in[2];
    const float* b1  = (const float*)d_in[3];
    const float* W1r = (const float*)d_in[4];
    const float* W2l = (const float*)d_in[5];
    const float* b2  = (const float*)d_in[6];
    const float* W2r = (const float*)d_in[7];
    const float* W3l = (const float*)d_in[8];
    const float* b3  = (const float*)d_in[9];
    const float* W3r = (const float*)d_in[10];
    float* out = (float*)d_out;

    char* ws = (char*)d_ws;
    size_t off = 0;
    auto alloc = [&](size_t bytes) { void* p = ws + off; off += (bytes + 255) & ~(size_t)255; return p; };
    int*   eidx    = (int*)  alloc((size_t)EE * 4);
    int*   rowptr  = (int*)  alloc((size_t)(NN + 1) * 4);
    int*   pos     = (int*)  alloc((size_t)NN * 4);
    int*   cnt     = (int*)  alloc((size_t)NN * 4);
    int*   bsums   = (int*)  alloc((size_t)N_SBLOCKS * 4);
    float* inv_cnt = (float*)alloc((size_t)NN * 4);
    float* agg     = (float*)alloc((size_t)NN * DD * 4);
    float* h1      = (float*)alloc((size_t)NN * DD * 4);

    hipMemsetAsync(cnt, 0, (size_t)NN * 4, stream);
    hist_kernel<<<(EE + 255) / 256, 256, 0, stream>>>(dstp, cnt, EE);
    block_reduce_kernel<<<N_SBLOCKS, SCAN_BLK, 0, stream>>>(cnt, bsums, NN);
    scan_bsums_kernel<<<1, SCAN_BLK, 0, stream>>>(bsums, N_SBLOCKS);
    block_scan_kernel<<<N_SBLOCKS, SCAN_BLK, 0, stream>>>(cnt, bsums, rowptr, pos, inv_cnt, NN, EE);
    bucket_kernel<<<(EE + 255) / 256, 256, 0, stream>>>(srcp, dstp, pos, eidx, EE);

    const int agg_grid = (NN + 3) / 4;
    const int lin_grid = (NN + 31) / 32;

    // layer 1: x -> h1 (ReLU)
    agg_kernel<<<agg_grid, 256, 0, stream>>>(x, eidx, rowptr, inv_cnt, agg, NN);
    linear_kernel<1><<<lin_grid, 256, 0, stream>>>(agg, x, W1l, W1r, b1, h1, NN);

    // layer 2: h1 -> d_out (ReLU)
    agg_kernel<<<agg_grid, 256, 0, stream>>>(h1, eidx, rowptr, inv_cnt, agg, NN);
    linear_kernel<1><<<lin_grid, 256, 0, stream>>>(agg, h1, W2l, W2r, b2, out, NN);

    // layer 3: d_out -> d_out (no ReLU; in-place safe via LDS staging)
    agg_kernel<<<agg_grid, 256, 0, stream>>>(out, eidx, rowptr, inv_cnt, agg, NN);
    linear_kernel<0><<<lin_grid, 256, 0, stream>>>(agg, out, W3l, W3r, b3, out, NN);
}

// Round 3
// 512.736 us; speedup vs baseline: 2.4688x; 1.8619x over previous
//
#include <hip/hip_runtime.h>

#define NN 50000
#define DD 128
#define EE 800000
#define SCAN_BLK 256
#define N_SBLOCKS ((NN + SCAN_BLK - 1) / SCAN_BLK)   // 196

// ---------------- CSR build ----------------
__global__ void hist_kernel(const int* __restrict__ dst, int* __restrict__ cnt, int E) {
    int e = blockIdx.x * blockDim.x + threadIdx.x;
    if (e < E) atomicAdd(&cnt[dst[e]], 1);
}

__global__ __launch_bounds__(SCAN_BLK) void block_reduce_kernel(const int* __restrict__ cnt,
                                                                int* __restrict__ bsums, int n) {
    __shared__ int s[SCAN_BLK];
    int i = blockIdx.x * SCAN_BLK + threadIdx.x;
    int v = (i < n) ? cnt[i] : 0;
    s[threadIdx.x] = v;
    __syncthreads();
    for (int off = SCAN_BLK / 2; off > 0; off >>= 1) {
        if (threadIdx.x < (unsigned)off) s[threadIdx.x] += s[threadIdx.x + off];
        __syncthreads();
    }
    if (threadIdx.x == 0) bsums[blockIdx.x] = s[0];
}

__global__ __launch_bounds__(SCAN_BLK) void scan_bsums_kernel(int* __restrict__ bsums, int nb) {
    __shared__ int s[SCAN_BLK];
    int v = (threadIdx.x < (unsigned)nb) ? bsums[threadIdx.x] : 0;
    s[threadIdx.x] = v;
    __syncthreads();
    for (int off = 1; off < SCAN_BLK; off <<= 1) {
        int t = (threadIdx.x >= (unsigned)off) ? s[threadIdx.x - off] : 0;
        __syncthreads();
        s[threadIdx.x] += t;
        __syncthreads();
    }
    if (threadIdx.x < (unsigned)nb) bsums[threadIdx.x] = s[threadIdx.x] - v;  // exclusive
}

__global__ __launch_bounds__(SCAN_BLK) void block_scan_kernel(const int* __restrict__ cnt,
                                                              const int* __restrict__ bsums,
                                                              int* __restrict__ rowptr,
                                                              int* __restrict__ pos,
                                                              float* __restrict__ inv_cnt,
                                                              int n, int E) {
    __shared__ int s[SCAN_BLK];
    int i = blockIdx.x * SCAN_BLK + threadIdx.x;
    int v = (i < n) ? cnt[i] : 0;
    s[threadIdx.x] = v;
    __syncthreads();
    for (int off = 1; off < SCAN_BLK; off <<= 1) {
        int t = (threadIdx.x >= (unsigned)off) ? s[threadIdx.x - off] : 0;
        __syncthreads();
        s[threadIdx.x] += t;
        __syncthreads();
    }
    int excl = bsums[blockIdx.x] + s[threadIdx.x] - v;
    if (i < n) {
        rowptr[i] = excl;
        pos[i]    = excl;
        inv_cnt[i] = (v > 0) ? (1.0f / (float)v) : 0.0f;
        if (i == n - 1) rowptr[n] = E;
    }
}

__global__ void bucket_kernel(const int* __restrict__ src, const int* __restrict__ dst,
                              int* __restrict__ pos, int* __restrict__ eidx, int E) {
    int e = blockIdx.x * blockDim.x + threadIdx.x;
    if (e < E) {
        int p = atomicAdd(&pos[dst[e]], 1);
        eidx[p] = src[e];
    }
}

// ---------------- weight prep: Bt[256][128], Bt[k][c] = k<128 ? Wl[c][k] : Wr[c][k-128]
__global__ __launch_bounds__(256) void wtrans_kernel(const float* __restrict__ Wl,
                                                     const float* __restrict__ Wr,
                                                     float* __restrict__ Bt) {
    int gid = blockIdx.x * 256 + threadIdx.x;  // 0..32767
    int k = gid >> 7;
    int c = gid & 127;
    float v = (k < 128) ? Wl[(size_t)c * DD + k] : Wr[(size_t)c * DD + (k - 128)];
    Bt[gid] = v;
}

// ---------------- mean aggregation (one wave per node, half-wave per edge-parity)
__global__ __launch_bounds__(256) void agg_kernel(const float* __restrict__ h,
                                                  const int* __restrict__ eidx,
                                                  const int* __restrict__ rowptr,
                                                  const float* __restrict__ inv_cnt,
                                                  float* __restrict__ agg, int n) {
    int node = blockIdx.x * 4 + (threadIdx.x >> 6);
    if (node >= n) return;
    int lane = threadIdx.x & 63;
    int half = lane >> 5;
    int q = lane & 31;
    int s0 = rowptr[node], s1 = rowptr[node + 1];
    float4 acc = {0.f, 0.f, 0.f, 0.f};
    int e = s0 + half;
    while (e + 2 < s1) {
        int sA = eidx[e], sB = eidx[e + 2];
        float4 vA = ((const float4*)(h + (size_t)sA * DD))[q];
        float4 vB = ((const float4*)(h + (size_t)sB * DD))[q];
        acc.x += vA.x + vB.x; acc.y += vA.y + vB.y;
        acc.z += vA.z + vB.z; acc.w += vA.w + vB.w;
        e += 4;
    }
    if (e < s1) {
        int sA = eidx[e];
        float4 vA = ((const float4*)(h + (size_t)sA * DD))[q];
        acc.x += vA.x; acc.y += vA.y; acc.z += vA.z; acc.w += vA.w;
    }
    acc.x += __shfl_xor(acc.x, 32);
    acc.y += __shfl_xor(acc.y, 32);
    acc.z += __shfl_xor(acc.z, 32);
    acc.w += __shfl_xor(acc.w, 32);
    if (half == 0) {
        float inv = inv_cnt[node];
        float4 o = {acc.x * inv, acc.y * inv, acc.z * inv, acc.w * inv};
        ((float4*)(agg + (size_t)node * DD))[q] = o;
    }
}

// ---------------- GEMM: out[n][c] = sum_k [agg|h][n][k] * Bt[k][c] + b[c]  (opt ReLU)
// 64 rows x 128 cols per block, 256 threads, 4x8 micro-tile, BK=32.
// In-place safe (h==out): each block reads/writes only its own 64 rows.
template <int RELU>
__global__ __launch_bounds__(256) void gemm_kernel(const float* __restrict__ agg,
                                                   const float* __restrict__ h,
                                                   const float* __restrict__ Bt,
                                                   const float* __restrict__ bias,
                                                   float* __restrict__ out, int n) {
    __shared__ float sA[64][36];    // [row][k], pad 36 -> aligned float4 stores, 4-stride banks on reads
    __shared__ float sB[32][128];   // [k][col]
    const int row0 = blockIdx.x * 64;
    const int tid = threadIdx.x;
    const int rb = (tid >> 4) << 2;   // 0..60
    const int cb = (tid & 15) << 3;   // 0..120

    float acc[4][8] = {};

    for (int phase = 0; phase < 2; ++phase) {
        const float* __restrict__ A = phase ? h : agg;
#pragma unroll 1
        for (int kt = 0; kt < 4; ++kt) {
            const int k0 = kt << 5;
            // stage A-tile: 64 rows x 32 k (coalesced float4 loads)
#pragma unroll
            for (int j = 0; j < 2; ++j) {
                int idx = tid + j * 256;      // 0..511
                int r = idx >> 3;             // 0..63
                int q = idx & 7;              // float4 slot within 32 k
                float4 v = {0.f, 0.f, 0.f, 0.f};
                if (row0 + r < n) v = *(const float4*)(A + (size_t)(row0 + r) * DD + k0 + (q << 2));
                *(float4*)&sA[r][q << 2] = v;
            }
            // stage B-tile: 32 k x 128 c (fully coalesced)
#pragma unroll
            for (int j = 0; j < 4; ++j) {
                int idx = tid + j * 256;      // 0..1023
                int k = idx >> 5;             // 0..31
                int c4 = (idx & 31) << 2;
                float4 v = *(const float4*)(Bt + (size_t)((phase << 7) + k0 + k) * DD + c4);
                *(float4*)&sB[k][c4] = v;
            }
            __syncthreads();
#pragma unroll 8
            for (int kk = 0; kk < 32; ++kk) {
                float a0 = sA[rb + 0][kk];
                float a1 = sA[rb + 1][kk];
                float a2 = sA[rb + 2][kk];
                float a3 = sA[rb + 3][kk];
                float4 b0 = *(const float4*)&sB[kk][cb];
                float4 b1 = *(const float4*)&sB[kk][cb + 4];
                float av[4] = {a0, a1, a2, a3};
                float bv[8] = {b0.x, b0.y, b0.z, b0.w, b1.x, b1.y, b1.z, b1.w};
#pragma unroll
                for (int r = 0; r < 4; ++r)
#pragma unroll
                    for (int c = 0; c < 8; ++c)
                        acc[r][c] += av[r] * bv[c];
            }
            __syncthreads();
        }
    }

    float4 bb0 = *(const float4*)(bias + cb);
    float4 bb1 = *(const float4*)(bias + cb + 4);
    float bv[8] = {bb0.x, bb0.y, bb0.z, bb0.w, bb1.x, bb1.y, bb1.z, bb1.w};
#pragma unroll
    for (int r = 0; r < 4; ++r) {
        int gr = row0 + rb + r;
        if (gr < n) {
            float o[8];
#pragma unroll
            for (int c = 0; c < 8; ++c) {
                float v = acc[r][c] + bv[c];
                if (RELU) v = fmaxf(v, 0.f);
                o[c] = v;
            }
            *(float4*)(out + (size_t)gr * DD + cb)     = make_float4(o[0], o[1], o[2], o[3]);
            *(float4*)(out + (size_t)gr * DD + cb + 4) = make_float4(o[4], o[5], o[6], o[7]);
        }
    }
}

extern "C" void kernel_launch(void* const* d_in, const int* in_sizes, int n_in,
                              void* d_out, int out_size, void* d_ws, size_t ws_size,
                              hipStream_t stream) {
    const float* x    = (const float*)d_in[0];
    const int*   edge = (const int*)d_in[1];     // [2, E] int32
    const int*   srcp = edge;
    const int*   dstp = edge + EE;
    const float* W1l = (const float*)d_in[2];
    const float* b1  = (const float*)d_in[3];
    const float* W1r = (const float*)d_in[4];
    const float* W2l = (const float*)d_in[5];
    const float* b2  = (const float*)d_in[6];
    const float* W2r = (const float*)d_in[7];
    const float* W3l = (const float*)d_in[8];
    const float* b3  = (const float*)d_in[9];
    const float* W3r = (const float*)d_in[10];
    float* out = (float*)d_out;

    char* ws = (char*)d_ws;
    size_t off = 0;
    auto alloc = [&](size_t bytes) { void* p = ws + off; off += (bytes + 255) & ~(size_t)255; return p; };
    int*   eidx    = (int*)  alloc((size_t)EE * 4);
    int*   rowptr  = (int*)  alloc((size_t)(NN + 1) * 4);
    int*   pos     = (int*)  alloc((size_t)NN * 4);
    int*   cnt     = (int*)  alloc((size_t)NN * 4);
    int*   bsums   = (int*)  alloc((size_t)N_SBLOCKS * 4);
    float* inv_cnt = (float*)alloc((size_t)NN * 4);
    float* Bt1     = (float*)alloc((size_t)256 * DD * 4);
    float* Bt2     = (float*)alloc((size_t)256 * DD * 4);
    float* Bt3     = (float*)alloc((size_t)256 * DD * 4);
    float* agg     = (float*)alloc((size_t)NN * DD * 4);
    float* h1      = (float*)alloc((size_t)NN * DD * 4);

    hipMemsetAsync(cnt, 0, (size_t)NN * 4, stream);
    hist_kernel<<<(EE + 255) / 256, 256, 0, stream>>>(dstp, cnt, EE);
    block_reduce_kernel<<<N_SBLOCKS, SCAN_BLK, 0, stream>>>(cnt, bsums, NN);
    scan_bsums_kernel<<<1, SCAN_BLK, 0, stream>>>(bsums, N_SBLOCKS);
    block_scan_kernel<<<N_SBLOCKS, SCAN_BLK, 0, stream>>>(cnt, bsums, rowptr, pos, inv_cnt, NN, EE);
    bucket_kernel<<<(EE + 255) / 256, 256, 0, stream>>>(srcp, dstp, pos, eidx, EE);

    wtrans_kernel<<<128, 256, 0, stream>>>(W1l, W1r, Bt1);
    wtrans_kernel<<<128, 256, 0, stream>>>(W2l, W2r, Bt2);
    wtrans_kernel<<<128, 256, 0, stream>>>(W3l, W3r, Bt3);

    const int agg_grid  = (NN + 3) / 4;
    const int gemm_grid = (NN + 63) / 64;

    // layer 1: x -> h1 (ReLU)
    agg_kernel<<<agg_grid, 256, 0, stream>>>(x, eidx, rowptr, inv_cnt, agg, NN);
    gemm_kernel<1><<<gemm_grid, 256, 0, stream>>>(agg, x, Bt1, b1, h1, NN);

    // layer 2: h1 -> d_out (ReLU)
    agg_kernel<<<agg_grid, 256, 0, stream>>>(h1, eidx, rowptr, inv_cnt, agg, NN);
    gemm_kernel<1><<<gemm_grid, 256, 0, stream>>>(agg, h1, Bt2, b2, out, NN);

    // layer 3: d_out -> d_out (no ReLU)
    agg_kernel<<<agg_grid, 256, 0, stream>>>(out, eidx, rowptr, inv_cnt, agg, NN);
    gemm_kernel<0><<<gemm_grid, 256, 0, stream>>>(agg, out, Bt3, b3, out, NN);
}

// Round 4
// 413.254 us; speedup vs baseline: 3.0631x; 1.2407x over previous
//
#include <hip/hip_runtime.h>

#define NN 50000
#define DD 128
#define EE 800000
#define SCAN_BLK 256
#define N_SBLOCKS ((NN + SCAN_BLK - 1) / SCAN_BLK)   // 196

typedef short bf16x8 __attribute__((ext_vector_type(8)));   // 8 bf16 = 4 VGPRs (guide §3)
typedef float f32x4  __attribute__((ext_vector_type(4)));

// ---- bf16 helpers (RNE) ----
__device__ __forceinline__ unsigned short f2bf(float f) {
    union { float f; unsigned u; } c; c.f = f;
    unsigned r = c.u + 0x7fffu + ((c.u >> 16) & 1u);
    return (unsigned short)(r >> 16);
}
__device__ __forceinline__ float bflo(unsigned p) { union { unsigned u; float f; } c; c.u = p << 16; return c.f; }
__device__ __forceinline__ float bfhi(unsigned p) { union { unsigned u; float f; } c; c.u = p & 0xffff0000u; return c.f; }
__device__ __forceinline__ unsigned packbf(float a, float b) { return (unsigned)f2bf(a) | ((unsigned)f2bf(b) << 16); }

// ---------------- CSR build ----------------
__global__ void hist_kernel(const int* __restrict__ dst, int* __restrict__ cnt, int E) {
    int e = blockIdx.x * blockDim.x + threadIdx.x;
    if (e < E) atomicAdd(&cnt[dst[e]], 1);
}

__global__ __launch_bounds__(SCAN_BLK) void block_reduce_kernel(const int* __restrict__ cnt,
                                                                int* __restrict__ bsums, int n) {
    __shared__ int s[SCAN_BLK];
    int i = blockIdx.x * SCAN_BLK + threadIdx.x;
    int v = (i < n) ? cnt[i] : 0;
    s[threadIdx.x] = v;
    __syncthreads();
    for (int off = SCAN_BLK / 2; off > 0; off >>= 1) {
        if (threadIdx.x < (unsigned)off) s[threadIdx.x] += s[threadIdx.x + off];
        __syncthreads();
    }
    if (threadIdx.x == 0) bsums[blockIdx.x] = s[0];
}

__global__ __launch_bounds__(SCAN_BLK) void scan_bsums_kernel(int* __restrict__ bsums, int nb) {
    __shared__ int s[SCAN_BLK];
    int v = (threadIdx.x < (unsigned)nb) ? bsums[threadIdx.x] : 0;
    s[threadIdx.x] = v;
    __syncthreads();
    for (int off = 1; off < SCAN_BLK; off <<= 1) {
        int t = (threadIdx.x >= (unsigned)off) ? s[threadIdx.x - off] : 0;
        __syncthreads();
        s[threadIdx.x] += t;
        __syncthreads();
    }
    if (threadIdx.x < (unsigned)nb) bsums[threadIdx.x] = s[threadIdx.x] - v;  // exclusive
}

__global__ __launch_bounds__(SCAN_BLK) void block_scan_kernel(const int* __restrict__ cnt,
                                                              const int* __restrict__ bsums,
                                                              int* __restrict__ rowptr,
                                                              int* __restrict__ pos,
                                                              float* __restrict__ inv_cnt,
                                                              int n, int E) {
    __shared__ int s[SCAN_BLK];
    int i = blockIdx.x * SCAN_BLK + threadIdx.x;
    int v = (i < n) ? cnt[i] : 0;
    s[threadIdx.x] = v;
    __syncthreads();
    for (int off = 1; off < SCAN_BLK; off <<= 1) {
        int t = (threadIdx.x >= (unsigned)off) ? s[threadIdx.x - off] : 0;
        __syncthreads();
        s[threadIdx.x] += t;
        __syncthreads();
    }
    int excl = bsums[blockIdx.x] + s[threadIdx.x] - v;
    if (i < n) {
        rowptr[i] = excl;
        pos[i]    = excl;
        inv_cnt[i] = (v > 0) ? (1.0f / (float)v) : 0.0f;
        if (i == n - 1) rowptr[n] = E;
    }
}

__global__ void bucket_kernel(const int* __restrict__ src, const int* __restrict__ dst,
                              int* __restrict__ pos, int* __restrict__ eidx, int E) {
    int e = blockIdx.x * blockDim.x + threadIdx.x;
    if (e < E) {
        int p = atomicAdd(&pos[dst[e]], 1);
        eidx[p] = src[e];
    }
}

// ---------------- fp32 -> bf16 convert (x) ----------------
__global__ __launch_bounds__(256) void cvt_kernel(const float* __restrict__ x,
                                                  unsigned short* __restrict__ xb, int n4) {
    int i = blockIdx.x * 256 + threadIdx.x;
    if (i < n4) {
        float4 v = ((const float4*)x)[i];
        uint2 o;
        o.x = packbf(v.x, v.y);
        o.y = packbf(v.z, v.w);
        ((uint2*)xb)[i] = o;
    }
}

// ---------------- weight prep: Bw[c][k] bf16, c in [0,128), k in [0,256) ----------------
// Bw[c][k] = k<128 ? Wl[c][k] : Wr[c][k-128]   (k-contiguous rows -> b128 B-fragments)
__global__ __launch_bounds__(256) void wcat_kernel(const float* __restrict__ Wl,
                                                   const float* __restrict__ Wr,
                                                   unsigned short* __restrict__ Bw) {
    int gid = blockIdx.x * 256 + threadIdx.x;  // 0..32767
    int c = gid >> 8;
    int k = gid & 255;
    float v = (k < 128) ? Wl[(size_t)c * DD + k] : Wr[(size_t)c * DD + (k - 128)];
    Bw[gid] = f2bf(v);
}

// ---------------- mean aggregation (bf16 rows, fp32 accumulate) ----------------
// One wave per node. Half-wave (32 lanes x 8B uint2 = 256B) covers one bf16 row;
// halves take even/odd edges; 2x unroll -> 4 row-loads in flight.
__global__ __launch_bounds__(256) void agg_kernel(const unsigned short* __restrict__ h,
                                                  const int* __restrict__ eidx,
                                                  const int* __restrict__ rowptr,
                                                  const float* __restrict__ inv_cnt,
                                                  unsigned short* __restrict__ aggb, int n) {
    int node = blockIdx.x * 4 + (threadIdx.x >> 6);
    if (node >= n) return;
    int lane = threadIdx.x & 63;
    int half = lane >> 5;
    int q = lane & 31;          // uint2 slot (4 bf16) within the row
    int s0 = rowptr[node], s1 = rowptr[node + 1];
    float a0 = 0.f, a1 = 0.f, a2 = 0.f, a3 = 0.f;
    int e = s0 + half;
    while (e + 2 < s1) {
        int sA = eidx[e], sB = eidx[e + 2];
        uint2 vA = ((const uint2*)(h + (size_t)sA * DD))[q];
        uint2 vB = ((const uint2*)(h + (size_t)sB * DD))[q];
        a0 += bflo(vA.x) + bflo(vB.x);
        a1 += bfhi(vA.x) + bfhi(vB.x);
        a2 += bflo(vA.y) + bflo(vB.y);
        a3 += bfhi(vA.y) + bfhi(vB.y);
        e += 4;
    }
    if (e < s1) {
        int sA = eidx[e];
        uint2 vA = ((const uint2*)(h + (size_t)sA * DD))[q];
        a0 += bflo(vA.x); a1 += bfhi(vA.x);
        a2 += bflo(vA.y); a3 += bfhi(vA.y);
    }
    a0 += __shfl_xor(a0, 32);
    a1 += __shfl_xor(a1, 32);
    a2 += __shfl_xor(a2, 32);
    a3 += __shfl_xor(a3, 32);
    if (half == 0) {
        float inv = inv_cnt[node];
        uint2 o;
        o.x = packbf(a0 * inv, a1 * inv);
        o.y = packbf(a2 * inv, a3 * inv);
        ((uint2*)(aggb + (size_t)node * DD))[q] = o;
    }
}

// ---------------- MFMA GEMM: out[n][c] = sum_k [aggb|hb][n][k] * Bw[c][k] + bias[c] ----------------
// mfma_f32_16x16x32_bf16. Wave tile = 16 rows x 128 cols (8 col-tiles), K=256 in 8 steps.
// Block = 4 waves = 64 rows. Pure-register (no LDS). Layouts (m89/m91-verified):
//   A-frag: lane holds A[m=lane&15][k0 + (lane>>4)*8 + j], j=0..7  -> b128 from k-contiguous rows
//   B-frag: lane holds B[k0 + (lane>>4)*8 + j][n=lane&15] = Bw[n][k...] -> b128 from Bw rows
//   C/D:    col = lane&15, row = (lane>>4)*4 + reg
template <int RELU, int WRITE_F32>
__global__ __launch_bounds__(256) void gemm_kernel(const unsigned short* __restrict__ aggb,
                                                   const unsigned short* __restrict__ hb,
                                                   const unsigned short* __restrict__ Bw,
                                                   const float* __restrict__ bias,
                                                   float* __restrict__ outf,
                                                   unsigned short* __restrict__ outb, int n) {
    const int lane = threadIdx.x & 63;
    const int wv   = threadIdx.x >> 6;      // 0..3
    const int m    = lane & 15;
    const int quad = lane >> 4;             // 0..3
    const int row0 = blockIdx.x * 64;
    const int arow = row0 + wv * 16 + m;    // A-operand row for this lane
    const bool rv = (arow < n);

    f32x4 acc[8];
#pragma unroll
    for (int ct = 0; ct < 8; ++ct) acc[ct] = (f32x4){0.f, 0.f, 0.f, 0.f};

#pragma unroll
    for (int ph = 0; ph < 2; ++ph) {
        const unsigned short* __restrict__ A = ph ? hb : aggb;
        const unsigned short* aptr = A + (size_t)arow * DD + quad * 8;
#pragma unroll
        for (int ks = 0; ks < 4; ++ks) {
            bf16x8 af = {0, 0, 0, 0, 0, 0, 0, 0};
            if (rv) af = *(const bf16x8*)(aptr + ks * 32);
            const int koff = ph * 128 + ks * 32 + quad * 8;
#pragma unroll
            for (int ct = 0; ct < 8; ++ct) {
                const int c = ct * 16 + m;
                bf16x8 bfv = *(const bf16x8*)(Bw + (size_t)c * 256 + koff);
                acc[ct] = __builtin_amdgcn_mfma_f32_16x16x32_bf16(af, bfv, acc[ct], 0, 0, 0);
            }
        }
    }

#pragma unroll
    for (int ct = 0; ct < 8; ++ct) {
        const int gcol = ct * 16 + m;
        const float bv = bias[gcol];
#pragma unroll
        for (int r = 0; r < 4; ++r) {
            const int grow = row0 + wv * 16 + quad * 4 + r;
            if (grow < n) {
                float v = acc[ct][r] + bv;
                if (RELU) v = fmaxf(v, 0.f);
                if (WRITE_F32) outf[(size_t)grow * DD + gcol] = v;
                else           outb[(size_t)grow * DD + gcol] = f2bf(v);
            }
        }
    }
}

extern "C" void kernel_launch(void* const* d_in, const int* in_sizes, int n_in,
                              void* d_out, int out_size, void* d_ws, size_t ws_size,
                              hipStream_t stream) {
    const float* x    = (const float*)d_in[0];
    const int*   edge = (const int*)d_in[1];     // [2, E] int32
    const int*   srcp = edge;
    const int*   dstp = edge + EE;
    const float* W1l = (const float*)d_in[2];
    const float* b1  = (const float*)d_in[3];
    const float* W1r = (const float*)d_in[4];
    const float* W2l = (const float*)d_in[5];
    const float* b2  = (const float*)d_in[6];
    const float* W2r = (const float*)d_in[7];
    const float* W3l = (const float*)d_in[8];
    const float* b3  = (const float*)d_in[9];
    const float* W3r = (const float*)d_in[10];
    float* out = (float*)d_out;

    char* ws = (char*)d_ws;
    size_t off = 0;
    auto alloc = [&](size_t bytes) { void* p = ws + off; off += (bytes + 255) & ~(size_t)255; return p; };
    int*   eidx    = (int*)  alloc((size_t)EE * 4);
    int*   rowptr  = (int*)  alloc((size_t)(NN + 1) * 4);
    int*   pos     = (int*)  alloc((size_t)NN * 4);
    int*   cnt     = (int*)  alloc((size_t)NN * 4);
    int*   bsums   = (int*)  alloc((size_t)N_SBLOCKS * 4);
    float* inv_cnt = (float*)alloc((size_t)NN * 4);
    unsigned short* Bw1  = (unsigned short*)alloc((size_t)DD * 256 * 2);
    unsigned short* Bw2  = (unsigned short*)alloc((size_t)DD * 256 * 2);
    unsigned short* Bw3  = (unsigned short*)alloc((size_t)DD * 256 * 2);
    unsigned short* xb   = (unsigned short*)alloc((size_t)NN * DD * 2);
    unsigned short* aggb = (unsigned short*)alloc((size_t)NN * DD * 2);
    unsigned short* h1b  = (unsigned short*)alloc((size_t)NN * DD * 2);
    unsigned short* h2b  = (unsigned short*)alloc((size_t)NN * DD * 2);

    hipMemsetAsync(cnt, 0, (size_t)NN * 4, stream);
    hist_kernel<<<(EE + 255) / 256, 256, 0, stream>>>(dstp, cnt, EE);
    block_reduce_kernel<<<N_SBLOCKS, SCAN_BLK, 0, stream>>>(cnt, bsums, NN);
    scan_bsums_kernel<<<1, SCAN_BLK, 0, stream>>>(bsums, N_SBLOCKS);
    block_scan_kernel<<<N_SBLOCKS, SCAN_BLK, 0, stream>>>(cnt, bsums, rowptr, pos, inv_cnt, NN, EE);
    bucket_kernel<<<(EE + 255) / 256, 256, 0, stream>>>(srcp, dstp, pos, eidx, EE);

    cvt_kernel<<<(NN * DD / 4 + 255) / 256, 256, 0, stream>>>(x, xb, NN * DD / 4);
    wcat_kernel<<<128, 256, 0, stream>>>(W1l, W1r, Bw1);
    wcat_kernel<<<128, 256, 0, stream>>>(W2l, W2r, Bw2);
    wcat_kernel<<<128, 256, 0, stream>>>(W3l, W3r, Bw3);

    const int agg_grid  = (NN + 3) / 4;
    const int gemm_grid = (NN + 63) / 64;

    // layer 1: xb -> h1b (ReLU)
    agg_kernel<<<agg_grid, 256, 0, stream>>>(xb, eidx, rowptr, inv_cnt, aggb, NN);
    gemm_kernel<1, 0><<<gemm_grid, 256, 0, stream>>>(aggb, xb, Bw1, b1, nullptr, h1b, NN);

    // layer 2: h1b -> h2b (ReLU)
    agg_kernel<<<agg_grid, 256, 0, stream>>>(h1b, eidx, rowptr, inv_cnt, aggb, NN);
    gemm_kernel<1, 0><<<gemm_grid, 256, 0, stream>>>(aggb, h1b, Bw2, b2, nullptr, h2b, NN);

    // layer 3: h2b -> out fp32 (no ReLU)
    agg_kernel<<<agg_grid, 256, 0, stream>>>(h2b, eidx, rowptr, inv_cnt, aggb, NN);
    gemm_kernel<0, 1><<<gemm_grid, 256, 0, stream>>>(aggb, h2b, Bw3, b3, out, nullptr, NN);
}